// Round 10
// baseline (733.481 us; speedup 1.0000x reference)
//
#include <hip/hip_runtime.h>
#include <math.h>

#define NNODES 100000
typedef unsigned short bf16_t;

typedef __attribute__((ext_vector_type(8))) short bf16x8;
typedef __attribute__((ext_vector_type(4))) float f32x4;

#define LOG2E 1.44269504f
#define THR2 11.5415603f       // 8 * log2e
#define C6 (0.6f * LOG2E)      // linear leaky coef (folded into row scalars)
#define C4 (0.4f * LOG2E)      // abs leaky coef (per-channel)

// ---------- bf16 helpers ----------
__device__ __forceinline__ float bf_lo(unsigned u) { return __uint_as_float(u << 16); }
__device__ __forceinline__ float bf_hi(unsigned u) { return __uint_as_float(u & 0xffff0000u); }
__device__ __forceinline__ bf16_t f2bf(float f) {
  unsigned u = __float_as_uint(f);
  return (bf16_t)((u + 0x7fffu + ((u >> 16) & 1u)) >> 16);
}
__device__ __forceinline__ float ex2(float x) {  // native 2^x
  float r;
  asm("v_exp_f32 %0, %1" : "=v"(r) : "v"(x));
  return r;
}

#define LDK 68  // padded LDS k-stride (bf16): 2-way bank aliasing max (free)

// ---------- MFMA GEMM with in-row scalar epilogue ----------
// Row layout (stride RB bytes): [channels bf16][head scalars].
// Scalar_h = C6 * sum_c att[h][c] * stored_bf16_x[c]  (from the STORED values).
// HM=0: 64-col table, 8 heads x 8ch, scalars f32 at scal_off.
// HM=1: each 64-col block is ONE head, scalar bf16 at scal_off + (ct>>6)*2.
template <int HM>
__global__ __launch_bounds__(256) void gemm_mfma(const float* __restrict__ in,
                                                 const float* __restrict__ Wl,
                                                 const float* __restrict__ Wr,
                                                 const float* __restrict__ att,
                                                 char* __restrict__ XLb,
                                                 char* __restrict__ XRb,
                                                 int n, int fo, int col0,
                                                 unsigned RB, int scal_off) {
  __shared__ bf16_t sX[64][LDK];  // [row][k]
  __shared__ bf16_t sL[64][LDK];  // W transposed: [col][k]
  __shared__ bf16_t sR[64][LDK];
  int r0 = blockIdx.x * 64;
  int ct = blockIdx.y * 64;
  for (int i = threadIdx.x; i < 64 * 64; i += 256) {
    int r = i >> 6, k = i & 63;
    float v = (r0 + r < n) ? in[(size_t)(r0 + r) * 64 + k] : 0.f;
    sX[r][k] = f2bf(v);
  }
  for (int i = threadIdx.x; i < 64 * 64; i += 256) {
    int k = i >> 6, c = i & 63;
    int gc = col0 + ct + c;
    sL[c][k] = f2bf(Wl[k * fo + gc]);
    sR[c][k] = f2bf(Wr[k * fo + gc]);
  }
  __syncthreads();
  int w = threadIdx.x >> 6, l = threadIdx.x & 63;
  int l16 = l & 15, kg = l >> 4;
  bf16x8 a0 = *(const bf16x8*)&sX[w * 16 + l16][kg * 8];
  bf16x8 a1 = *(const bf16x8*)&sX[w * 16 + l16][kg * 8 + 32];
  f32x4 accL[4], accR[4];
#pragma unroll
  for (int nt = 0; nt < 4; ++nt) {
#pragma unroll
    for (int r = 0; r < 4; ++r) { accL[nt][r] = 0.f; accR[nt][r] = 0.f; }
  }
#pragma unroll
  for (int nt = 0; nt < 4; ++nt) {
    bf16x8 bl0 = *(const bf16x8*)&sL[nt * 16 + l16][kg * 8];
    bf16x8 bl1 = *(const bf16x8*)&sL[nt * 16 + l16][kg * 8 + 32];
    bf16x8 br0 = *(const bf16x8*)&sR[nt * 16 + l16][kg * 8];
    bf16x8 br1 = *(const bf16x8*)&sR[nt * 16 + l16][kg * 8 + 32];
    accL[nt] = __builtin_amdgcn_mfma_f32_16x16x32_bf16(a0, bl0, accL[nt], 0, 0, 0);
    accL[nt] = __builtin_amdgcn_mfma_f32_16x16x32_bf16(a1, bl1, accL[nt], 0, 0, 0);
    accR[nt] = __builtin_amdgcn_mfma_f32_16x16x32_bf16(a0, br0, accR[nt], 0, 0, 0);
    accR[nt] = __builtin_amdgcn_mfma_f32_16x16x32_bf16(a1, br1, accR[nt], 0, 0, 0);
  }
  float aw[4];
#pragma unroll
  for (int nt = 0; nt < 4; ++nt) aw[nt] = att[col0 + ct + nt * 16 + l16] * C6;
  int head1 = ct >> 6;  // HM=1: local head slot of this column block
#pragma unroll
  for (int r = 0; r < 4; ++r) {
    int grow = r0 + w * 16 + kg * 4 + r;
    bool ok = grow < n;
    char* rowL = XLb + (size_t)grow * RB;
    char* rowR = XRb + (size_t)grow * RB;
    float sLh = 0.f, sRh = 0.f;
#pragma unroll
    for (int nt = 0; nt < 4; ++nt) {
      bf16_t bl = f2bf(accL[nt][r]), br = f2bf(accR[nt][r]);
      float xl_ = __uint_as_float(((unsigned)bl) << 16);
      float xr_ = __uint_as_float(((unsigned)br) << 16);
      if (ok) {
        int chb = (ct + nt * 16 + l16) * 2;
        *(bf16_t*)(rowL + chb) = bl;
        *(bf16_t*)(rowR + chb) = br;
      }
      if (HM) {
        sLh += aw[nt] * xl_;
        sRh += aw[nt] * xr_;
      } else {
        float vL = aw[nt] * xl_, vR = aw[nt] * xr_;
        vL += __shfl_xor(vL, 1); vL += __shfl_xor(vL, 2); vL += __shfl_xor(vL, 4);
        vR += __shfl_xor(vR, 1); vR += __shfl_xor(vR, 2); vR += __shfl_xor(vR, 4);
        if ((l16 & 7) == 0 && ok) {
          int head = 2 * nt + (l16 >> 3);
          *(float*)(rowL + scal_off + head * 4) = vL;
          *(float*)(rowR + scal_off + head * 4) = vR;
        }
      }
    }
    if (HM) {
      sLh += __shfl_xor(sLh, 1); sLh += __shfl_xor(sLh, 2);
      sLh += __shfl_xor(sLh, 4); sLh += __shfl_xor(sLh, 8);
      sRh += __shfl_xor(sRh, 1); sRh += __shfl_xor(sRh, 2);
      sRh += __shfl_xor(sRh, 4); sRh += __shfl_xor(sRh, 8);
      if (l16 == 0 && ok) {
        *(bf16_t*)(rowL + scal_off + head1 * 2) = f2bf(sLh);
        *(bf16_t*)(rowR + scal_off + head1 * 2) = f2bf(sRh);
      }
    }
  }
}

// ---------- CSR build (atomic-free scatter via ranks) ----------
__global__ void zeroi(int* __restrict__ p, int n) {
  int i = blockIdx.x * blockDim.x + threadIdx.x;
  if (i < n) p[i] = 0;
}
__global__ void histrank(const int* __restrict__ ei, int E,
                         int* __restrict__ cnt, unsigned char* __restrict__ rank) {
  int e = blockIdx.x * blockDim.x + threadIdx.x;
  if (e < E) rank[e] = (unsigned char)atomicAdd(&cnt[ei[E + e]], 1);
}
__global__ void scan1(const int* __restrict__ cnt, int n,
                      int* __restrict__ scn, int* __restrict__ bsum) {
  __shared__ int sh[256];
  int t = threadIdx.x, i = blockIdx.x * 256 + t;
  int v = (i < n) ? cnt[i] : 0;
  sh[t] = v;
  __syncthreads();
  for (int off = 1; off < 256; off <<= 1) {
    int x = (t >= off) ? sh[t - off] : 0;
    __syncthreads();
    sh[t] += x;
    __syncthreads();
  }
  if (i < n) scn[i] = sh[t];
  if (t == 255) bsum[blockIdx.x] = sh[255];
}
__global__ void scan2(int* __restrict__ bsum, int nb) {
  __shared__ int sh[512];
  int t = threadIdx.x;
  sh[t] = (t < nb) ? bsum[t] : 0;
  __syncthreads();
  for (int off = 1; off < 512; off <<= 1) {
    int x = (t >= off) ? sh[t - off] : 0;
    __syncthreads();
    sh[t] += x;
    __syncthreads();
  }
  if (t < nb) bsum[t] = sh[t];
}
__global__ void scan3(int* __restrict__ RS, const int* __restrict__ bsum, int n) {
  int i = blockIdx.x * blockDim.x + threadIdx.x;
  if (i >= n) return;
  int b = i >> 8;
  int pre = (b > 0) ? bsum[b - 1] : 0;
  RS[i + 1] += pre;
  if (i == 0) RS[0] = 0;
}
__global__ void scat2(const int* __restrict__ ei, int E,
                      const int* __restrict__ RS,
                      const unsigned char* __restrict__ rank,
                      int* __restrict__ SRC) {
  int e = blockIdx.x * blockDim.x + threadIdx.x;
  if (e >= E) return;
  int d = ei[E + e];
  SRC[RS[d] + (int)rank[e]] = ei[e];
}

// ---------- fused layers 0/1 (C=8 concat): 4 dsts/wave; row = 160B (64ch + 8 f32) ----------
__global__ __launch_bounds__(256) void fused01(const char* __restrict__ xlb,
                                               const char* __restrict__ xrb,
                                               const float* __restrict__ att, // [8][8]
                                               const int* __restrict__ RS,
                                               const int* __restrict__ SRC,
                                               const float* __restrict__ bias,
                                               float* __restrict__ curbuf,
                                               int n, int addres) {
  int l = threadIdx.x & 63;
  int q = l & 15;      // channel quad: ch 4q..4q+3
  int h01 = q >> 1;    // head
  int d = blockIdx.x * 16 + ((threadIdx.x >> 6) << 2) + (l >> 4);
  int dd = (d < n) ? d : 0;
  float c0 = att[4 * q] * C4, c1 = att[4 * q + 1] * C4;
  float c2 = att[4 * q + 2] * C4, c3 = att[4 * q + 3] * C4;
  unsigned doff = (unsigned)dd * 160u;
  uint2 ur = *(const uint2*)(xrb + doff + (q << 3));
  float r0 = bf_lo(ur.x), r1 = bf_hi(ur.x), r2 = bf_lo(ur.y), r3 = bf_hi(ur.y);
  float ard = *(const float*)(xrb + doff + 128 + (h01 << 2));
  int rs = RS[dd], re = RS[dd + 1];
  int cnt = (d < n) ? (re - rs + 1) : 0;  // self loop + edges
  int mc = max(cnt, __shfl_xor(cnt, 16));
  mc = max(mc, __shfl_xor(mc, 32));
  float m = -1e30f, s = 0.f, ac0 = 0.f, ac1 = 0.f, ac2 = 0.f, ac3 = 0.f;
  int nsid = (rs < re) ? SRC[rs] : dd;
  uint2 u = *(const uint2*)(xlb + doff + (q << 3));
  float alc = *(const float*)(xlb + doff + 128 + (h01 << 2));
  for (int j = 0;;) {
    unsigned noff = (unsigned)nsid * 160u;
    uint2 un = *(const uint2*)(xlb + noff + (q << 3));
    float aln = *(const float*)(xlb + noff + 128 + (h01 << 2));
    int i2 = rs + j + 1;
    int nn = (i2 < re) ? SRC[i2] : dd;
    float x0 = bf_lo(u.x), x1 = bf_hi(u.x), x2 = bf_lo(u.y), x3 = bf_hi(u.y);
    float t = c0 * fabsf(x0 + r0) + c1 * fabsf(x1 + r1) +
              c2 * fabsf(x2 + r2) + c3 * fabsf(x3 + r3);
    t += __shfl_xor(t, 1);   // 8-ch head spans lane pair
    t += alc + ard;          // linear leaky terms
    if (j >= cnt) t = -1e30f;
    if (__any(t > m + THR2)) {  // rare exact rescale
      float nm = fmaxf(m, t);
      float e0 = ex2(m - nm);
      s *= e0; ac0 *= e0; ac1 *= e0; ac2 *= e0; ac3 *= e0; m = nm;
    }
    float e1 = ex2(t - m);
    s += e1;
    ac0 += e1 * x0; ac1 += e1 * x1; ac2 += e1 * x2; ac3 += e1 * x3;
    ++j;
    if (j >= mc) break;
    u = un;
    alc = aln;
    nsid = nn;
  }
  if (d < n) {
    float inv = 1.f / (s + 1e-16f);
    float v0 = ac0 * inv + bias[4 * q];
    float v1 = ac1 * inv + bias[4 * q + 1];
    float v2 = ac2 * inv + bias[4 * q + 2];
    float v3 = ac3 * inv + bias[4 * q + 3];
    v0 = v0 > 0.f ? v0 : expm1f(v0);
    v1 = v1 > 0.f ? v1 : expm1f(v1);
    v2 = v2 > 0.f ? v2 : expm1f(v2);
    v3 = v3 > 0.f ? v3 : expm1f(v3);
    float4* pc = (float4*)(curbuf + (size_t)d * 64 + 4 * q);
    if (addres) {
      float4 pr = *pc;
      v0 += pr.x; v1 += pr.y; v2 += pr.z; v3 += pr.w;
    }
    *pc = make_float4(v0, v1, v2, v3);
  }
}

// ---------- fused layer 2; NH=8: row 1040B (512ch + 8 bf16), 1 dst/wave ----------
// NH=4: row 528B (256ch + 4 bf16), 2 dsts/wave, two passes via accbuf.
template <int NH>
__global__ __launch_bounds__(256) void fused2(const char* __restrict__ xlb,
                                              const char* __restrict__ xrb,
                                              const float* __restrict__ att, // [8][64]
                                              const int* __restrict__ RS,
                                              const int* __restrict__ SRC,
                                              const float* __restrict__ bias,
                                              float* __restrict__ accbuf,
                                              float* __restrict__ outbuf,
                                              int n, int h0, int pass) {
  const unsigned RB = (NH == 8) ? 1040u : 528u;
  const int CHB = NH * 128;   // scalar slot base
  int l = threadIdx.x & 63;
  int ll = (NH == 8) ? l : (l & 31);
  int d = (NH == 8) ? blockIdx.x * 4 + (threadIdx.x >> 6)
                    : blockIdx.x * 8 + ((threadIdx.x >> 6) << 1) + (l >> 5);
  int dd = (d < n) ? d : 0;
  int h = ll >> 3, c0 = (ll & 7) * 8;
  int habs = h0 + h;
  const float* ap = att + habs * 64 + c0;
  float c[8];
#pragma unroll
  for (int k = 0; k < 8; ++k) c[k] = ap[k] * C4;
  unsigned doff = (unsigned)dd * RB;
  uint4 ur = *(const uint4*)(xrb + doff + (ll << 4));
  float r[8] = {bf_lo(ur.x), bf_hi(ur.x), bf_lo(ur.y), bf_hi(ur.y),
                bf_lo(ur.z), bf_hi(ur.z), bf_lo(ur.w), bf_hi(ur.w)};
  float ard = bf_lo((unsigned)*(const unsigned short*)(xrb + doff + CHB + (h << 1)));
  int rs = RS[dd], re = RS[dd + 1];
  int cnt = (d < n) ? (re - rs + 1) : 0;
  int maxcnt = (NH == 4) ? max(cnt, __shfl_xor(cnt, 32)) : cnt;
  float m = -1e30f, s = 0.f;
  float ac[8] = {0.f, 0.f, 0.f, 0.f, 0.f, 0.f, 0.f, 0.f};
  int nsid = (rs < re) ? SRC[rs] : dd;
  uint4 u = *(const uint4*)(xlb + doff + (ll << 4));
  float alc = bf_lo((unsigned)*(const unsigned short*)(xlb + doff + CHB + (h << 1)));
  for (int j = 0;;) {
    unsigned noff = (unsigned)nsid * RB;
    uint4 un = *(const uint4*)(xlb + noff + (ll << 4));
    float aln = bf_lo((unsigned)*(const unsigned short*)(xlb + noff + CHB + (h << 1)));
    int i2 = rs + j + 1;
    int nn = (i2 < re) ? SRC[i2] : dd;
    float x[8] = {bf_lo(u.x), bf_hi(u.x), bf_lo(u.y), bf_hi(u.y),
                  bf_lo(u.z), bf_hi(u.z), bf_lo(u.w), bf_hi(u.w)};
    float t = 0.f;
#pragma unroll
    for (int k = 0; k < 8; ++k) t += c[k] * fabsf(x[k] + r[k]);
    t += __shfl_xor(t, 1);
    t += __shfl_xor(t, 2);
    t += __shfl_xor(t, 4);
    t += alc + ard;
    if (NH == 4 && j >= cnt) t = -1e30f;   // lockstep mask (NH8 has none)
    if (__any(t > m + THR2)) {
      float nm = fmaxf(m, t);
      float e0 = ex2(m - nm);
      s *= e0;
#pragma unroll
      for (int k = 0; k < 8; ++k) ac[k] *= e0;
      m = nm;
    }
    float e1 = ex2(t - m);
    s += e1;
#pragma unroll
    for (int k = 0; k < 8; ++k) ac[k] += e1 * x[k];
    ++j;
    if (j >= maxcnt) break;
    u = un;
    alc = aln;
    nsid = nn;
  }
  float inv = 1.f / (s + 1e-16f);
  float v[8];
#pragma unroll
  for (int k = 0; k < 8; ++k) {
    v[k] = ac[k] * inv;
    v[k] += __shfl_xor(v[k], 8);    // sum heads
    v[k] += __shfl_xor(v[k], 16);
    if (NH == 8) v[k] += __shfl_xor(v[k], 32);
  }
  if (ll < 8 && d < n) {
    if (NH == 8) {
      const float* bp = bias + ll * 8;
      float4 o0, o1;
      o0.x = v[0] * 0.125f + bp[0];
      o0.y = v[1] * 0.125f + bp[1];
      o0.z = v[2] * 0.125f + bp[2];
      o0.w = v[3] * 0.125f + bp[3];
      o1.x = v[4] * 0.125f + bp[4];
      o1.y = v[5] * 0.125f + bp[5];
      o1.z = v[6] * 0.125f + bp[6];
      o1.w = v[7] * 0.125f + bp[7];
      float* po = outbuf + (size_t)d * 64 + ll * 8;
      *(float4*)po = o0;
      *(float4*)(po + 4) = o1;
    } else {
      float* pa = accbuf + (size_t)d * 64 + ll * 8;
      if (pass == 0) {
        *(float4*)pa = make_float4(v[0], v[1], v[2], v[3]);
        *(float4*)(pa + 4) = make_float4(v[4], v[5], v[6], v[7]);
      } else {
        float4 p0 = *(float4*)pa;
        float4 p1 = *(float4*)(pa + 4);
        const float* bp = bias + ll * 8;
        float4 o0, o1;
        o0.x = (p0.x + v[0]) * 0.125f + bp[0];
        o0.y = (p0.y + v[1]) * 0.125f + bp[1];
        o0.z = (p0.z + v[2]) * 0.125f + bp[2];
        o0.w = (p0.w + v[3]) * 0.125f + bp[3];
        o1.x = (p1.x + v[4]) * 0.125f + bp[4];
        o1.y = (p1.y + v[5]) * 0.125f + bp[5];
        o1.z = (p1.z + v[6]) * 0.125f + bp[6];
        o1.w = (p1.w + v[7]) * 0.125f + bp[7];
        float* po = outbuf + (size_t)d * 64 + ll * 8;
        *(float4*)po = o0;
        *(float4*)(po + 4) = o1;
      }
    }
  }
}

extern "C" void kernel_launch(void* const* d_in, const int* in_sizes, int n_in,
                              void* d_out, int out_size, void* d_ws, size_t ws_size,
                              hipStream_t stream) {
  const float* x = (const float*)d_in[0];
  const int* ei = (const int*)d_in[1];
  const float* Wmat[3][2] = {
      {(const float*)d_in[2], (const float*)d_in[3]},
      {(const float*)d_in[6], (const float*)d_in[7]},
      {(const float*)d_in[10], (const float*)d_in[11]}};
  const float* att[3] = {(const float*)d_in[4], (const float*)d_in[8],
                         (const float*)d_in[12]};
  const float* bias[3] = {(const float*)d_in[5], (const float*)d_in[9],
                          (const float*)d_in[13]};
  const int N = NNODES;
  int E = in_sizes[1] / 2;

  auto al = [](size_t b) { return (b + 255) & ~(size_t)255; };
  size_t fixed = al((size_t)N * 64 * 4)                       // CUR
               + al((size_t)(N + 1) * 4) + al((size_t)N * 4)  // RS + CNT
               + al(512 * 4) + al((size_t)E * 4) + al((size_t)E);  // BSUM+SRC+RANK
  size_t need8 = fixed + 2 * al((size_t)N * 1040);
  bool mode8 = (ws_size >= need8);

  char* p = (char*)d_ws;
  auto alloc = [&](size_t bytes) {
    char* r = p;
    p += (bytes + 255) & ~(size_t)255;
    return r;
  };
  float* CUR = (float*)alloc((size_t)N * 64 * 4);
  size_t xtab = mode8 ? (size_t)N * 1040 : (size_t)N * 528;
  char* XL = alloc(xtab);
  char* XR = alloc(xtab);
  int* RS = (int*)alloc((size_t)(N + 1) * 4);
  int* CNT = (int*)alloc((size_t)N * 4);
  int* BSUM = (int*)alloc(512 * 4);
  int* SRC = (int*)alloc((size_t)E * 4);
  unsigned char* RANK = (unsigned char*)alloc((size_t)E);
  float* ACC = mode8 ? nullptr : (float*)alloc((size_t)N * 64 * 4);

  const int nb = (N + 255) / 256;
  const int geblk = (E + 255) / 256;
  const int g01 = (N + 15) / 16;
  const int gx64 = (N + 63) / 64;

  // ---- CSR build ----
  zeroi<<<nb, 256, 0, stream>>>(CNT, N);
  histrank<<<geblk, 256, 0, stream>>>(ei, E, CNT, RANK);
  scan1<<<nb, 256, 0, stream>>>(CNT, N, RS + 1, BSUM);
  scan2<<<1, 512, 0, stream>>>(BSUM, nb);
  scan3<<<nb, 256, 0, stream>>>(RS, BSUM, N);
  scat2<<<geblk, 256, 0, stream>>>(ei, E, RS, RANK, SRC);

  // ---- layers 0 and 1 (row stride 160B, f32 scalars at +128) ----
  for (int layer = 0; layer < 2; ++layer) {
    const float* in = (layer == 0) ? x : CUR;
    gemm_mfma<0><<<dim3(gx64, 1), 256, 0, stream>>>(
        in, Wmat[layer][0], Wmat[layer][1], att[layer], XL, XR, N, 64, 0, 160u, 128);
    fused01<<<g01, 256, 0, stream>>>(XL, XR, att[layer], RS, SRC, bias[layer],
                                     CUR, N, layer);
  }

  // ---- layer 2 ----
  if (mode8) {
    gemm_mfma<1><<<dim3(gx64, 8), 256, 0, stream>>>(
        CUR, Wmat[2][0], Wmat[2][1], att[2], XL, XR, N, 512, 0, 1040u, 1024);
    fused2<8><<<(N + 3) / 4, 256, 0, stream>>>(XL, XR, att[2], RS, SRC, bias[2],
                                               nullptr, (float*)d_out, N, 0, 0);
  } else {
    for (int hb = 0; hb < 2; ++hb) {
      gemm_mfma<1><<<dim3(gx64, 4), 256, 0, stream>>>(
          CUR, Wmat[2][0], Wmat[2][1], att[2], XL, XR, N, 512, hb * 256, 528u, 512);
      fused2<4><<<(N + 7) / 8, 256, 0, stream>>>(XL, XR, att[2], RS, SRC, bias[2],
                                                 ACC, (float*)d_out, N, hb * 4, hb);
    }
  }
}

// Round 12
// 672.746 us; speedup vs baseline: 1.0903x; 1.0903x over previous
//
#include <hip/hip_runtime.h>
#include <hip/hip_fp16.h>
#include <math.h>

#define NNODES 100000

typedef _Float16 f16x2 __attribute__((ext_vector_type(2)));
typedef _Float16 f16x8 __attribute__((ext_vector_type(8)));
typedef float f32x4 __attribute__((ext_vector_type(4)));

#define LOG2E 1.44269504f
#define THR2 11.5415603f   // 8 * log2e

__device__ __forceinline__ float ex2(float x) {  // native 2^x
  float r;
  asm("v_exp_f32 %0, %1" : "=v"(r) : "v"(x));
  return r;
}
__device__ __forceinline__ f16x2 bch(unsigned x) {
  return __builtin_bit_cast(f16x2, x);
}
__device__ __forceinline__ float fdot2h(f16x2 a, f16x2 b, float c) {
#if __has_builtin(__builtin_amdgcn_fdot2)
  return __builtin_amdgcn_fdot2(a, b, c, false);
#else
  return c + (float)a.x * (float)b.x + (float)a.y * (float)b.y;
#endif
}
// acc(f32) += f16(lo/hi of xpk) * e(f32)  — single v_fma_mix_f32
__device__ __forceinline__ void fmix_lo(float& acc, unsigned xpk, float e) {
  asm("v_fma_mix_f32 %0, %1, %2, %0 op_sel_hi:[1,0,0]"
      : "+v"(acc) : "v"(xpk), "v"(e));
}
__device__ __forceinline__ void fmix_hi(float& acc, unsigned xpk, float e) {
  asm("v_fma_mix_f32 %0, %1, %2, %0 op_sel:[1,0,0] op_sel_hi:[1,0,0]"
      : "+v"(acc) : "v"(xpk), "v"(e));
}
// packed leaky-relu: max(v, 0.2*v) elementwise (v_pk_mul + v_pk_max)
__device__ __forceinline__ f16x2 pleaky(f16x2 v) {
  f16x2 w = v * (_Float16)0.2f;
  return __builtin_elementwise_max(v, w);
}

#define LDK 68  // padded LDS k-stride (f16): 2-way bank aliasing max (free)

// ---------- MFMA GEMM (f16): XL/XR rows [ncols f16], stride RB bytes ----------
__global__ __launch_bounds__(256) void gemm_mfma(const float* __restrict__ in,
                                                 const float* __restrict__ Wl,
                                                 const float* __restrict__ Wr,
                                                 char* __restrict__ XLb,
                                                 char* __restrict__ XRb,
                                                 int n, int fo, int col0,
                                                 unsigned RB) {
  __shared__ _Float16 sX[64][LDK];  // [row][k]
  __shared__ _Float16 sL[64][LDK];  // W transposed: [col][k]
  __shared__ _Float16 sR[64][LDK];
  int r0 = blockIdx.x * 64;
  int ct = blockIdx.y * 64;
  for (int i = threadIdx.x; i < 64 * 64; i += 256) {
    int r = i >> 6, k = i & 63;
    float v = (r0 + r < n) ? in[(size_t)(r0 + r) * 64 + k] : 0.f;
    sX[r][k] = (_Float16)v;
  }
  for (int i = threadIdx.x; i < 64 * 64; i += 256) {
    int k = i >> 6, c = i & 63;
    int gc = col0 + ct + c;
    sL[c][k] = (_Float16)Wl[k * fo + gc];
    sR[c][k] = (_Float16)Wr[k * fo + gc];
  }
  __syncthreads();
  int w = threadIdx.x >> 6, l = threadIdx.x & 63;
  int l16 = l & 15, kg = l >> 4;
  f16x8 a0 = *(const f16x8*)&sX[w * 16 + l16][kg * 8];
  f16x8 a1 = *(const f16x8*)&sX[w * 16 + l16][kg * 8 + 32];
  f32x4 accL[4], accR[4];
#pragma unroll
  for (int nt = 0; nt < 4; ++nt) {
#pragma unroll
    for (int r = 0; r < 4; ++r) { accL[nt][r] = 0.f; accR[nt][r] = 0.f; }
  }
#pragma unroll
  for (int nt = 0; nt < 4; ++nt) {
    f16x8 bl0 = *(const f16x8*)&sL[nt * 16 + l16][kg * 8];
    f16x8 bl1 = *(const f16x8*)&sL[nt * 16 + l16][kg * 8 + 32];
    f16x8 br0 = *(const f16x8*)&sR[nt * 16 + l16][kg * 8];
    f16x8 br1 = *(const f16x8*)&sR[nt * 16 + l16][kg * 8 + 32];
    accL[nt] = __builtin_amdgcn_mfma_f32_16x16x32_f16(a0, bl0, accL[nt], 0, 0, 0);
    accL[nt] = __builtin_amdgcn_mfma_f32_16x16x32_f16(a1, bl1, accL[nt], 0, 0, 0);
    accR[nt] = __builtin_amdgcn_mfma_f32_16x16x32_f16(a0, br0, accR[nt], 0, 0, 0);
    accR[nt] = __builtin_amdgcn_mfma_f32_16x16x32_f16(a1, br1, accR[nt], 0, 0, 0);
  }
  // D layout: col = l&15, row = (l>>4)*4 + reg
#pragma unroll
  for (int r = 0; r < 4; ++r) {
    int grow = r0 + w * 16 + kg * 4 + r;
    if (grow >= n) continue;
    char* rowL = XLb + (size_t)grow * RB;
    char* rowR = XRb + (size_t)grow * RB;
#pragma unroll
    for (int nt = 0; nt < 4; ++nt) {
      int chb = (ct + nt * 16 + l16) * 2;
      *(_Float16*)(rowL + chb) = (_Float16)accL[nt][r];
      *(_Float16*)(rowR + chb) = (_Float16)accR[nt][r];
    }
  }
}

// ---------- CSR build (atomic-free scatter via ranks) ----------
__global__ void zeroi(int* __restrict__ p, int n) {
  int i = blockIdx.x * blockDim.x + threadIdx.x;
  if (i < n) p[i] = 0;
}
__global__ void histrank(const int* __restrict__ ei, int E,
                         int* __restrict__ cnt, unsigned char* __restrict__ rank) {
  int e = blockIdx.x * blockDim.x + threadIdx.x;
  if (e < E) rank[e] = (unsigned char)atomicAdd(&cnt[ei[E + e]], 1);
}
__global__ void scan1(const int* __restrict__ cnt, int n,
                      int* __restrict__ scn, int* __restrict__ bsum) {
  __shared__ int sh[256];
  int t = threadIdx.x, i = blockIdx.x * 256 + t;
  int v = (i < n) ? cnt[i] : 0;
  sh[t] = v;
  __syncthreads();
  for (int off = 1; off < 256; off <<= 1) {
    int x = (t >= off) ? sh[t - off] : 0;
    __syncthreads();
    sh[t] += x;
    __syncthreads();
  }
  if (i < n) scn[i] = sh[t];
  if (t == 255) bsum[blockIdx.x] = sh[255];
}
__global__ void scan2(int* __restrict__ bsum, int nb) {
  __shared__ int sh[512];
  int t = threadIdx.x;
  sh[t] = (t < nb) ? bsum[t] : 0;
  __syncthreads();
  for (int off = 1; off < 512; off <<= 1) {
    int x = (t >= off) ? sh[t - off] : 0;
    __syncthreads();
    sh[t] += x;
    __syncthreads();
  }
  if (t < nb) bsum[t] = sh[t];
}
__global__ void scan3(int* __restrict__ RS, const int* __restrict__ bsum, int n) {
  int i = blockIdx.x * blockDim.x + threadIdx.x;
  if (i >= n) return;
  int b = i >> 8;
  int pre = (b > 0) ? bsum[b - 1] : 0;
  RS[i + 1] += pre;
  if (i == 0) RS[0] = 0;
}
__global__ void scat2(const int* __restrict__ ei, int E,
                      const int* __restrict__ RS,
                      const unsigned char* __restrict__ rank,
                      int* __restrict__ SRC) {
  int e = blockIdx.x * blockDim.x + threadIdx.x;
  if (e >= E) return;
  int d = ei[E + e];
  SRC[RS[d] + (int)rank[e]] = ei[e];
}

// ---------- fused layers 0/1 (C=8 concat): 4 dsts/wave; row = 128B f16 ----------
__global__ __launch_bounds__(256) void fused01(const char* __restrict__ xlb,
                                               const char* __restrict__ xrb,
                                               const float* __restrict__ att, // [8][8]
                                               const int* __restrict__ RS,
                                               const int* __restrict__ SRC,
                                               const float* __restrict__ bias,
                                               float* __restrict__ curbuf,
                                               int n, int addres) {
  int l = threadIdx.x & 63;
  int q = l & 15;  // channel quad: ch 4q..4q+3
  int d = blockIdx.x * 16 + ((threadIdx.x >> 6) << 2) + (l >> 4);
  int dd = (d < n) ? d : 0;
  f16x2 c2a = {(_Float16)(att[4 * q] * LOG2E), (_Float16)(att[4 * q + 1] * LOG2E)};
  f16x2 c2b = {(_Float16)(att[4 * q + 2] * LOG2E), (_Float16)(att[4 * q + 3] * LOG2E)};
  uint2 ur = *(const uint2*)(xrb + ((unsigned)dd << 7) + (q << 3));
  f16x2 r2a = bch(ur.x), r2b = bch(ur.y);
  int rs = RS[dd], re = RS[dd + 1];
  int cnt = (d < n) ? (re - rs + 1) : 0;  // self loop + edges
  int mc = max(cnt, __shfl_xor(cnt, 16));
  mc = max(mc, __shfl_xor(mc, 32));
  float m = -1e30f, s = 0.f, ac0 = 0.f, ac1 = 0.f, ac2 = 0.f, ac3 = 0.f;
  int nsid = (rs < re) ? SRC[rs] : dd;
  uint2 u = *(const uint2*)(xlb + ((unsigned)dd << 7) + (q << 3));
  for (int j = 0;;) {
    uint2 un = *(const uint2*)(xlb + ((unsigned)nsid << 7) + (q << 3));
    int i2 = rs + j + 1;
    int nn = (i2 < re) ? SRC[i2] : dd;
    f16x2 la = pleaky(bch(u.x) + r2a);
    f16x2 lb = pleaky(bch(u.y) + r2b);
    float t = fdot2h(la, c2a, 0.f);
    t = fdot2h(lb, c2b, t);
    t += __shfl_xor(t, 1);  // 8-ch head spans lane pair
    if (j >= cnt) t = -1e30f;
    if (__any(t > m + THR2)) {  // rare exact rescale
      float nm = fmaxf(m, t);
      float e0 = ex2(m - nm);
      s *= e0; ac0 *= e0; ac1 *= e0; ac2 *= e0; ac3 *= e0; m = nm;
    }
    float e1 = ex2(t - m);
    s += e1;
    fmix_lo(ac0, u.x, e1);
    fmix_hi(ac1, u.x, e1);
    fmix_lo(ac2, u.y, e1);
    fmix_hi(ac3, u.y, e1);
    ++j;
    if (j >= mc) break;
    u = un;
    nsid = nn;
  }
  if (d < n) {
    float inv = 1.f / (s + 1e-16f);
    float v0 = ac0 * inv + bias[4 * q];
    float v1 = ac1 * inv + bias[4 * q + 1];
    float v2 = ac2 * inv + bias[4 * q + 2];
    float v3 = ac3 * inv + bias[4 * q + 3];
    v0 = v0 > 0.f ? v0 : expm1f(v0);
    v1 = v1 > 0.f ? v1 : expm1f(v1);
    v2 = v2 > 0.f ? v2 : expm1f(v2);
    v3 = v3 > 0.f ? v3 : expm1f(v3);
    float4* pc = (float4*)(curbuf + (size_t)d * 64 + 4 * q);
    if (addres) {
      float4 pr = *pc;
      v0 += pr.x; v1 += pr.y; v2 += pr.z; v3 += pr.w;
    }
    *pc = make_float4(v0, v1, v2, v3);
  }
}

// ---------- fused layer 2; NH=8: row 1024B, 1 dst/wave; NH=4: row 512B, 2 dsts/wave ----------
template <int NH>
__global__ __launch_bounds__(256) void fused2(const char* __restrict__ xlb,
                                              const char* __restrict__ xrb,
                                              const float* __restrict__ att, // [8][64]
                                              const int* __restrict__ RS,
                                              const int* __restrict__ SRC,
                                              const float* __restrict__ bias,
                                              float* __restrict__ accbuf,
                                              float* __restrict__ outbuf,
                                              int n, int h0, int pass) {
  constexpr int RSH = (NH == 8) ? 10 : 9;  // log2(row bytes)
  int l = threadIdx.x & 63;
  int ll = (NH == 8) ? l : (l & 31);
  int d = (NH == 8) ? blockIdx.x * 4 + (threadIdx.x >> 6)
                    : blockIdx.x * 8 + ((threadIdx.x >> 6) << 1) + (l >> 5);
  int dd = (d < n) ? d : 0;
  int h = ll >> 3, c0 = (ll & 7) * 8;
  const float* ap = att + (h0 + h) * 64 + c0;
  f16x2 c2[4];
#pragma unroll
  for (int k = 0; k < 4; ++k)
    c2[k] = f16x2{(_Float16)(ap[2 * k] * LOG2E), (_Float16)(ap[2 * k + 1] * LOG2E)};
  uint4 ur = *(const uint4*)(xrb + ((unsigned)dd << RSH) + (ll << 4));
  f16x2 r2[4] = {bch(ur.x), bch(ur.y), bch(ur.z), bch(ur.w)};
  int rs = RS[dd], re = RS[dd + 1];
  int cnt = (d < n) ? (re - rs + 1) : 0;
  int maxcnt = (NH == 4) ? max(cnt, __shfl_xor(cnt, 32)) : cnt;
  float m = -1e30f, s = 0.f;
  float ac[8] = {0.f, 0.f, 0.f, 0.f, 0.f, 0.f, 0.f, 0.f};
  int nsid = (rs < re) ? SRC[rs] : dd;
  uint4 u = *(const uint4*)(xlb + ((unsigned)dd << RSH) + (ll << 4));
  for (int j = 0;;) {
    uint4 un = *(const uint4*)(xlb + ((unsigned)nsid << RSH) + (ll << 4));
    int i2 = rs + j + 1;
    int nn = (i2 < re) ? SRC[i2] : dd;
    f16x2 l0 = pleaky(bch(u.x) + r2[0]);
    f16x2 l1 = pleaky(bch(u.y) + r2[1]);
    f16x2 l2 = pleaky(bch(u.z) + r2[2]);
    f16x2 l3 = pleaky(bch(u.w) + r2[3]);
    float t = fdot2h(l0, c2[0], 0.f);
    t = fdot2h(l1, c2[1], t);
    t = fdot2h(l2, c2[2], t);
    t = fdot2h(l3, c2[3], t);
    t += __shfl_xor(t, 1);
    t += __shfl_xor(t, 2);
    t += __shfl_xor(t, 4);
    if (NH == 4 && j >= cnt) t = -1e30f;   // lockstep mask (NH8 has none)
    if (__any(t > m + THR2)) {
      float nm = fmaxf(m, t);
      float e0 = ex2(m - nm);
      s *= e0;
#pragma unroll
      for (int k = 0; k < 8; ++k) ac[k] *= e0;
      m = nm;
    }
    float e1 = ex2(t - m);
    s += e1;
    fmix_lo(ac[0], u.x, e1);
    fmix_hi(ac[1], u.x, e1);
    fmix_lo(ac[2], u.y, e1);
    fmix_hi(ac[3], u.y, e1);
    fmix_lo(ac[4], u.z, e1);
    fmix_hi(ac[5], u.z, e1);
    fmix_lo(ac[6], u.w, e1);
    fmix_hi(ac[7], u.w, e1);
    ++j;
    if (j >= maxcnt) break;
    u = un;
    nsid = nn;
  }
  float inv = 1.f / (s + 1e-16f);
  float v[8];
#pragma unroll
  for (int k = 0; k < 8; ++k) {
    v[k] = ac[k] * inv;
    v[k] += __shfl_xor(v[k], 8);    // sum heads
    v[k] += __shfl_xor(v[k], 16);
    if (NH == 8) v[k] += __shfl_xor(v[k], 32);
  }
  if (ll < 8 && d < n) {
    if (NH == 8) {
      const float* bp = bias + ll * 8;
      float4 o0, o1;
      o0.x = v[0] * 0.125f + bp[0];
      o0.y = v[1] * 0.125f + bp[1];
      o0.z = v[2] * 0.125f + bp[2];
      o0.w = v[3] * 0.125f + bp[3];
      o1.x = v[4] * 0.125f + bp[4];
      o1.y = v[5] * 0.125f + bp[5];
      o1.z = v[6] * 0.125f + bp[6];
      o1.w = v[7] * 0.125f + bp[7];
      float* po = outbuf + (size_t)d * 64 + ll * 8;
      *(float4*)po = o0;
      *(float4*)(po + 4) = o1;
    } else {
      float* pa = accbuf + (size_t)d * 64 + ll * 8;
      if (pass == 0) {
        *(float4*)pa = make_float4(v[0], v[1], v[2], v[3]);
        *(float4*)(pa + 4) = make_float4(v[4], v[5], v[6], v[7]);
      } else {
        float4 p0 = *(float4*)pa;
        float4 p1 = *(float4*)(pa + 4);
        const float* bp = bias + ll * 8;
        float4 o0, o1;
        o0.x = (p0.x + v[0]) * 0.125f + bp[0];
        o0.y = (p0.y + v[1]) * 0.125f + bp[1];
        o0.z = (p0.z + v[2]) * 0.125f + bp[2];
        o0.w = (p0.w + v[3]) * 0.125f + bp[3];
        o1.x = (p1.x + v[4]) * 0.125f + bp[4];
        o1.y = (p1.y + v[5]) * 0.125f + bp[5];
        o1.z = (p1.z + v[6]) * 0.125f + bp[6];
        o1.w = (p1.w + v[7]) * 0.125f + bp[7];
        float* po = outbuf + (size_t)d * 64 + ll * 8;
        *(float4*)po = o0;
        *(float4*)(po + 4) = o1;
      }
    }
  }
}

extern "C" void kernel_launch(void* const* d_in, const int* in_sizes, int n_in,
                              void* d_out, int out_size, void* d_ws, size_t ws_size,
                              hipStream_t stream) {
  const float* x = (const float*)d_in[0];
  const int* ei = (const int*)d_in[1];
  const float* Wmat[3][2] = {
      {(const float*)d_in[2], (const float*)d_in[3]},
      {(const float*)d_in[6], (const float*)d_in[7]},
      {(const float*)d_in[10], (const float*)d_in[11]}};
  const float* att[3] = {(const float*)d_in[4], (const float*)d_in[8],
                         (const float*)d_in[12]};
  const float* bias[3] = {(const float*)d_in[5], (const float*)d_in[9],
                          (const float*)d_in[13]};
  const int N = NNODES;
  int E = in_sizes[1] / 2;

  auto al = [](size_t b) { return (b + 255) & ~(size_t)255; };
  size_t fixed = al((size_t)N * 64 * 4)                       // CUR
               + al((size_t)(N + 1) * 4) + al((size_t)N * 4)  // RS + CNT
               + al(512 * 4) + al((size_t)E * 4) + al((size_t)E);  // BSUM+SRC+RANK
  size_t need8 = fixed + 2 * al((size_t)N * 1024);
  bool mode8 = (ws_size >= need8);

  char* p = (char*)d_ws;
  auto alloc = [&](size_t bytes) {
    char* r = p;
    p += (bytes + 255) & ~(size_t)255;
    return r;
  };
  float* CUR = (float*)alloc((size_t)N * 64 * 4);
  size_t xtab = mode8 ? (size_t)N * 1024 : (size_t)N * 512;
  char* XL = alloc(xtab);
  char* XR = alloc(xtab);
  int* RS = (int*)alloc((size_t)(N + 1) * 4);
  int* CNT = (int*)alloc((size_t)N * 4);
  int* BSUM = (int*)alloc(512 * 4);
  int* SRC = (int*)alloc((size_t)E * 4);
  unsigned char* RANK = (unsigned char*)alloc((size_t)E);
  float* ACC = mode8 ? nullptr : (float*)alloc((size_t)N * 64 * 4);

  const int nb = (N + 255) / 256;
  const int geblk = (E + 255) / 256;
  const int g01 = (N + 15) / 16;
  const int gx64 = (N + 63) / 64;

  // ---- CSR build ----
  zeroi<<<nb, 256, 0, stream>>>(CNT, N);
  histrank<<<geblk, 256, 0, stream>>>(ei, E, CNT, RANK);
  scan1<<<nb, 256, 0, stream>>>(CNT, N, RS + 1, BSUM);
  scan2<<<1, 512, 0, stream>>>(BSUM, nb);
  scan3<<<nb, 256, 0, stream>>>(RS, BSUM, N);
  scat2<<<geblk, 256, 0, stream>>>(ei, E, RS, RANK, SRC);

  // ---- layers 0 and 1 (row stride 128B f16) ----
  for (int layer = 0; layer < 2; ++layer) {
    const float* in = (layer == 0) ? x : CUR;
    gemm_mfma<<<dim3(gx64, 1), 256, 0, stream>>>(
        in, Wmat[layer][0], Wmat[layer][1], XL, XR, N, 64, 0, 128u);
    fused01<<<g01, 256, 0, stream>>>(XL, XR, att[layer], RS, SRC, bias[layer],
                                     CUR, N, layer);
  }

  // ---- layer 2 ----
  if (mode8) {
    gemm_mfma<<<dim3(gx64, 8), 256, 0, stream>>>(
        CUR, Wmat[2][0], Wmat[2][1], XL, XR, N, 512, 0, 1024u);
    fused2<8><<<(N + 3) / 4, 256, 0, stream>>>(XL, XR, att[2], RS, SRC, bias[2],
                                               nullptr, (float*)d_out, N, 0, 0);
  } else {
    for (int hb = 0; hb < 2; ++hb) {
      gemm_mfma<<<dim3(gx64, 4), 256, 0, stream>>>(
          CUR, Wmat[2][0], Wmat[2][1], XL, XR, N, 512, hb * 256, 512u);
      fused2<4><<<(N + 7) / 8, 256, 0, stream>>>(XL, XR, att[2], RS, SRC, bias[2],
                                                 ACC, (float*)d_out, N, hb * 4, hb);
    }
  }
}

// Round 13
// 663.284 us; speedup vs baseline: 1.1058x; 1.0143x over previous
//
#include <hip/hip_runtime.h>
#include <hip/hip_fp16.h>
#include <math.h>

#define NNODES 100000

typedef _Float16 f16x2 __attribute__((ext_vector_type(2)));
typedef _Float16 f16x8 __attribute__((ext_vector_type(8)));
typedef float f32x4 __attribute__((ext_vector_type(4)));

#define LOG2E 1.44269504f
#define THR2 11.5415603f   // 8 * log2e

__device__ __forceinline__ float ex2(float x) {  // native 2^x
  float r;
  asm("v_exp_f32 %0, %1" : "=v"(r) : "v"(x));
  return r;
}
__device__ __forceinline__ f16x2 bch(unsigned x) {
  return __builtin_bit_cast(f16x2, x);
}
__device__ __forceinline__ float fdot2h(f16x2 a, f16x2 b, float c) {
#if __has_builtin(__builtin_amdgcn_fdot2)
  return __builtin_amdgcn_fdot2(a, b, c, false);
#else
  return c + (float)a.x * (float)b.x + (float)a.y * (float)b.y;
#endif
}
// acc(f32) += f16(lo/hi of xpk) * e(f32)  — single v_fma_mix_f32
__device__ __forceinline__ void fmix_lo(float& acc, unsigned xpk, float e) {
  asm("v_fma_mix_f32 %0, %1, %2, %0 op_sel_hi:[1,0,0]"
      : "+v"(acc) : "v"(xpk), "v"(e));
}
__device__ __forceinline__ void fmix_hi(float& acc, unsigned xpk, float e) {
  asm("v_fma_mix_f32 %0, %1, %2, %0 op_sel:[1,0,0] op_sel_hi:[1,0,0]"
      : "+v"(acc) : "v"(xpk), "v"(e));
}
// packed leaky-relu: max(v, 0.2*v) elementwise (v_pk_mul + v_pk_max)
__device__ __forceinline__ f16x2 pleaky(f16x2 v) {
  f16x2 w = v * (_Float16)0.2f;
  return __builtin_elementwise_max(v, w);
}

#define LDK 68  // padded LDS k-stride (f16): 2-way bank aliasing max (free)

// ---------- MFMA GEMM (f16): XL/XR rows [ncols f16], stride RB bytes ----------
__global__ __launch_bounds__(256) void gemm_mfma(const float* __restrict__ in,
                                                 const float* __restrict__ Wl,
                                                 const float* __restrict__ Wr,
                                                 char* __restrict__ XLb,
                                                 char* __restrict__ XRb,
                                                 int n, int fo, int col0,
                                                 unsigned RB) {
  __shared__ _Float16 sX[64][LDK];  // [row][k]
  __shared__ _Float16 sL[64][LDK];  // W transposed: [col][k]
  __shared__ _Float16 sR[64][LDK];
  int r0 = blockIdx.x * 64;
  int ct = blockIdx.y * 64;
  for (int i = threadIdx.x; i < 64 * 64; i += 256) {
    int r = i >> 6, k = i & 63;
    float v = (r0 + r < n) ? in[(size_t)(r0 + r) * 64 + k] : 0.f;
    sX[r][k] = (_Float16)v;
  }
  for (int i = threadIdx.x; i < 64 * 64; i += 256) {
    int k = i >> 6, c = i & 63;
    int gc = col0 + ct + c;
    sL[c][k] = (_Float16)Wl[k * fo + gc];
    sR[c][k] = (_Float16)Wr[k * fo + gc];
  }
  __syncthreads();
  int w = threadIdx.x >> 6, l = threadIdx.x & 63;
  int l16 = l & 15, kg = l >> 4;
  f16x8 a0 = *(const f16x8*)&sX[w * 16 + l16][kg * 8];
  f16x8 a1 = *(const f16x8*)&sX[w * 16 + l16][kg * 8 + 32];
  f32x4 accL[4], accR[4];
#pragma unroll
  for (int nt = 0; nt < 4; ++nt) {
#pragma unroll
    for (int r = 0; r < 4; ++r) { accL[nt][r] = 0.f; accR[nt][r] = 0.f; }
  }
#pragma unroll
  for (int nt = 0; nt < 4; ++nt) {
    f16x8 bl0 = *(const f16x8*)&sL[nt * 16 + l16][kg * 8];
    f16x8 bl1 = *(const f16x8*)&sL[nt * 16 + l16][kg * 8 + 32];
    f16x8 br0 = *(const f16x8*)&sR[nt * 16 + l16][kg * 8];
    f16x8 br1 = *(const f16x8*)&sR[nt * 16 + l16][kg * 8 + 32];
    accL[nt] = __builtin_amdgcn_mfma_f32_16x16x32_f16(a0, bl0, accL[nt], 0, 0, 0);
    accL[nt] = __builtin_amdgcn_mfma_f32_16x16x32_f16(a1, bl1, accL[nt], 0, 0, 0);
    accR[nt] = __builtin_amdgcn_mfma_f32_16x16x32_f16(a0, br0, accR[nt], 0, 0, 0);
    accR[nt] = __builtin_amdgcn_mfma_f32_16x16x32_f16(a1, br1, accR[nt], 0, 0, 0);
  }
  // D layout: col = l&15, row = (l>>4)*4 + reg
#pragma unroll
  for (int r = 0; r < 4; ++r) {
    int grow = r0 + w * 16 + kg * 4 + r;
    if (grow >= n) continue;
    char* rowL = XLb + (size_t)grow * RB;
    char* rowR = XRb + (size_t)grow * RB;
#pragma unroll
    for (int nt = 0; nt < 4; ++nt) {
      int chb = (ct + nt * 16 + l16) * 2;
      *(_Float16*)(rowL + chb) = (_Float16)accL[nt][r];
      *(_Float16*)(rowR + chb) = (_Float16)accR[nt][r];
    }
  }
}

// ---------- CSR build (atomic-free scatter via ranks) ----------
__global__ void zeroi(int* __restrict__ p, int n) {
  int i = blockIdx.x * blockDim.x + threadIdx.x;
  if (i < n) p[i] = 0;
}
__global__ void histrank(const int* __restrict__ ei, int E,
                         int* __restrict__ cnt, unsigned char* __restrict__ rank) {
  int e = blockIdx.x * blockDim.x + threadIdx.x;
  if (e < E) rank[e] = (unsigned char)atomicAdd(&cnt[ei[E + e]], 1);
}
__global__ void scan1(const int* __restrict__ cnt, int n,
                      int* __restrict__ scn, int* __restrict__ bsum) {
  __shared__ int sh[256];
  int t = threadIdx.x, i = blockIdx.x * 256 + t;
  int v = (i < n) ? cnt[i] : 0;
  sh[t] = v;
  __syncthreads();
  for (int off = 1; off < 256; off <<= 1) {
    int x = (t >= off) ? sh[t - off] : 0;
    __syncthreads();
    sh[t] += x;
    __syncthreads();
  }
  if (i < n) scn[i] = sh[t];
  if (t == 255) bsum[blockIdx.x] = sh[255];
}
__global__ void scan2(int* __restrict__ bsum, int nb) {
  __shared__ int sh[512];
  int t = threadIdx.x;
  sh[t] = (t < nb) ? bsum[t] : 0;
  __syncthreads();
  for (int off = 1; off < 512; off <<= 1) {
    int x = (t >= off) ? sh[t - off] : 0;
    __syncthreads();
    sh[t] += x;
    __syncthreads();
  }
  if (t < nb) bsum[t] = sh[t];
}
__global__ void scan3(int* __restrict__ RS, const int* __restrict__ bsum, int n) {
  int i = blockIdx.x * blockDim.x + threadIdx.x;
  if (i >= n) return;
  int b = i >> 8;
  int pre = (b > 0) ? bsum[b - 1] : 0;
  RS[i + 1] += pre;
  if (i == 0) RS[0] = 0;
}
__global__ void scat2(const int* __restrict__ ei, int E,
                      const int* __restrict__ RS,
                      const unsigned char* __restrict__ rank,
                      int* __restrict__ SRC) {
  int e = blockIdx.x * blockDim.x + threadIdx.x;
  if (e >= E) return;
  int d = ei[E + e];
  SRC[RS[d] + (int)rank[e]] = ei[e];
}

// ---------- fused layers 0/1 (C=8 concat): 4 dsts/wave; row = 128B f16 ----------
// depth-2 row prefetch: rows for edges j, j+1, j+2 live; ids fetched 3 ahead.
__global__ __launch_bounds__(256) void fused01(const char* __restrict__ xlb,
                                               const char* __restrict__ xrb,
                                               const float* __restrict__ att, // [8][8]
                                               const int* __restrict__ RS,
                                               const int* __restrict__ SRC,
                                               const float* __restrict__ bias,
                                               float* __restrict__ curbuf,
                                               int n, int addres) {
  int l = threadIdx.x & 63;
  int q = l & 15;  // channel quad: ch 4q..4q+3
  int d = blockIdx.x * 16 + ((threadIdx.x >> 6) << 2) + (l >> 4);
  int dd = (d < n) ? d : 0;
  f16x2 c2a = {(_Float16)(att[4 * q] * LOG2E), (_Float16)(att[4 * q + 1] * LOG2E)};
  f16x2 c2b = {(_Float16)(att[4 * q + 2] * LOG2E), (_Float16)(att[4 * q + 3] * LOG2E)};
  uint2 ur = *(const uint2*)(xrb + ((unsigned)dd << 7) + (q << 3));
  f16x2 r2a = bch(ur.x), r2b = bch(ur.y);
  int rs = RS[dd], re = RS[dd + 1];
  int cnt = (d < n) ? (re - rs + 1) : 0;  // self loop + edges
  int mc = max(cnt, __shfl_xor(cnt, 16));
  mc = max(mc, __shfl_xor(mc, 32));
  float m = -1e30f, s = 0.f, ac0 = 0.f, ac1 = 0.f, ac2 = 0.f, ac3 = 0.f;
  int id1 = (rs < re) ? SRC[rs] : dd;
  uint2 u0 = *(const uint2*)(xlb + ((unsigned)dd << 7) + (q << 3));
  uint2 u1 = *(const uint2*)(xlb + ((unsigned)id1 << 7) + (q << 3));
  int id2 = (rs + 1 < re) ? SRC[rs + 1] : dd;
  for (int j = 0;;) {
    uint2 u2 = *(const uint2*)(xlb + ((unsigned)id2 << 7) + (q << 3));
    int i3 = rs + j + 2;
    int id3 = (i3 < re) ? SRC[i3] : dd;
    f16x2 la = pleaky(bch(u0.x) + r2a);
    f16x2 lb = pleaky(bch(u0.y) + r2b);
    float t = fdot2h(la, c2a, 0.f);
    t = fdot2h(lb, c2b, t);
    t += __shfl_xor(t, 1);  // 8-ch head spans lane pair
    if (j >= cnt) t = -1e30f;
    if (__any(t > m + THR2)) {  // rare exact rescale
      float nm = fmaxf(m, t);
      float e0 = ex2(m - nm);
      s *= e0; ac0 *= e0; ac1 *= e0; ac2 *= e0; ac3 *= e0; m = nm;
    }
    float e1 = ex2(t - m);
    s += e1;
    fmix_lo(ac0, u0.x, e1);
    fmix_hi(ac1, u0.x, e1);
    fmix_lo(ac2, u0.y, e1);
    fmix_hi(ac3, u0.y, e1);
    ++j;
    if (j >= mc) break;
    u0 = u1;
    u1 = u2;
    id2 = id3;
  }
  if (d < n) {
    float inv = 1.f / (s + 1e-16f);
    float v0 = ac0 * inv + bias[4 * q];
    float v1 = ac1 * inv + bias[4 * q + 1];
    float v2 = ac2 * inv + bias[4 * q + 2];
    float v3 = ac3 * inv + bias[4 * q + 3];
    v0 = v0 > 0.f ? v0 : expm1f(v0);
    v1 = v1 > 0.f ? v1 : expm1f(v1);
    v2 = v2 > 0.f ? v2 : expm1f(v2);
    v3 = v3 > 0.f ? v3 : expm1f(v3);
    float4* pc = (float4*)(curbuf + (size_t)d * 64 + 4 * q);
    if (addres) {
      float4 pr = *pc;
      v0 += pr.x; v1 += pr.y; v2 += pr.z; v3 += pr.w;
    }
    *pc = make_float4(v0, v1, v2, v3);
  }
}

// ---------- fused layer 2; NH=8: row 1024B, 1 dst/wave; NH=4: row 512B, 2 dsts/wave ----------
// depth-2 row prefetch as in fused01.
template <int NH>
__global__ __launch_bounds__(256) void fused2(const char* __restrict__ xlb,
                                              const char* __restrict__ xrb,
                                              const float* __restrict__ att, // [8][64]
                                              const int* __restrict__ RS,
                                              const int* __restrict__ SRC,
                                              const float* __restrict__ bias,
                                              float* __restrict__ accbuf,
                                              float* __restrict__ outbuf,
                                              int n, int h0, int pass) {
  constexpr int RSH = (NH == 8) ? 10 : 9;  // log2(row bytes)
  int l = threadIdx.x & 63;
  int ll = (NH == 8) ? l : (l & 31);
  int d = (NH == 8) ? blockIdx.x * 4 + (threadIdx.x >> 6)
                    : blockIdx.x * 8 + ((threadIdx.x >> 6) << 1) + (l >> 5);
  int dd = (d < n) ? d : 0;
  int h = ll >> 3, c0 = (ll & 7) * 8;
  const float* ap = att + (h0 + h) * 64 + c0;
  f16x2 c2[4];
#pragma unroll
  for (int k = 0; k < 4; ++k)
    c2[k] = f16x2{(_Float16)(ap[2 * k] * LOG2E), (_Float16)(ap[2 * k + 1] * LOG2E)};
  uint4 ur = *(const uint4*)(xrb + ((unsigned)dd << RSH) + (ll << 4));
  f16x2 r2[4] = {bch(ur.x), bch(ur.y), bch(ur.z), bch(ur.w)};
  int rs = RS[dd], re = RS[dd + 1];
  int cnt = (d < n) ? (re - rs + 1) : 0;
  int maxcnt = (NH == 4) ? max(cnt, __shfl_xor(cnt, 32)) : cnt;
  float m = -1e30f, s = 0.f;
  float ac[8] = {0.f, 0.f, 0.f, 0.f, 0.f, 0.f, 0.f, 0.f};
  int id1 = (rs < re) ? SRC[rs] : dd;
  uint4 u0 = *(const uint4*)(xlb + ((unsigned)dd << RSH) + (ll << 4));
  uint4 u1 = *(const uint4*)(xlb + ((unsigned)id1 << RSH) + (ll << 4));
  int id2 = (rs + 1 < re) ? SRC[rs + 1] : dd;
  for (int j = 0;;) {
    uint4 u2 = *(const uint4*)(xlb + ((unsigned)id2 << RSH) + (ll << 4));
    int i3 = rs + j + 2;
    int id3 = (i3 < re) ? SRC[i3] : dd;
    f16x2 l0 = pleaky(bch(u0.x) + r2[0]);
    f16x2 l1 = pleaky(bch(u0.y) + r2[1]);
    f16x2 l2 = pleaky(bch(u0.z) + r2[2]);
    f16x2 l3 = pleaky(bch(u0.w) + r2[3]);
    float t = fdot2h(l0, c2[0], 0.f);
    t = fdot2h(l1, c2[1], t);
    t = fdot2h(l2, c2[2], t);
    t = fdot2h(l3, c2[3], t);
    t += __shfl_xor(t, 1);
    t += __shfl_xor(t, 2);
    t += __shfl_xor(t, 4);
    if (NH == 4 && j >= cnt) t = -1e30f;   // lockstep mask (NH8 has none)
    if (__any(t > m + THR2)) {
      float nm = fmaxf(m, t);
      float e0 = ex2(m - nm);
      s *= e0;
#pragma unroll
      for (int k = 0; k < 8; ++k) ac[k] *= e0;
      m = nm;
    }
    float e1 = ex2(t - m);
    s += e1;
    fmix_lo(ac[0], u0.x, e1);
    fmix_hi(ac[1], u0.x, e1);
    fmix_lo(ac[2], u0.y, e1);
    fmix_hi(ac[3], u0.y, e1);
    fmix_lo(ac[4], u0.z, e1);
    fmix_hi(ac[5], u0.z, e1);
    fmix_lo(ac[6], u0.w, e1);
    fmix_hi(ac[7], u0.w, e1);
    ++j;
    if (j >= maxcnt) break;
    u0 = u1;
    u1 = u2;
    id2 = id3;
  }
  float inv = 1.f / (s + 1e-16f);
  float v[8];
#pragma unroll
  for (int k = 0; k < 8; ++k) {
    v[k] = ac[k] * inv;
    v[k] += __shfl_xor(v[k], 8);    // sum heads
    v[k] += __shfl_xor(v[k], 16);
    if (NH == 8) v[k] += __shfl_xor(v[k], 32);
  }
  if (ll < 8 && d < n) {
    if (NH == 8) {
      const float* bp = bias + ll * 8;
      float4 o0, o1;
      o0.x = v[0] * 0.125f + bp[0];
      o0.y = v[1] * 0.125f + bp[1];
      o0.z = v[2] * 0.125f + bp[2];
      o0.w = v[3] * 0.125f + bp[3];
      o1.x = v[4] * 0.125f + bp[4];
      o1.y = v[5] * 0.125f + bp[5];
      o1.z = v[6] * 0.125f + bp[6];
      o1.w = v[7] * 0.125f + bp[7];
      float* po = outbuf + (size_t)d * 64 + ll * 8;
      *(float4*)po = o0;
      *(float4*)(po + 4) = o1;
    } else {
      float* pa = accbuf + (size_t)d * 64 + ll * 8;
      if (pass == 0) {
        *(float4*)pa = make_float4(v[0], v[1], v[2], v[3]);
        *(float4*)(pa + 4) = make_float4(v[4], v[5], v[6], v[7]);
      } else {
        float4 p0 = *(float4*)pa;
        float4 p1 = *(float4*)(pa + 4);
        const float* bp = bias + ll * 8;
        float4 o0, o1;
        o0.x = (p0.x + v[0]) * 0.125f + bp[0];
        o0.y = (p0.y + v[1]) * 0.125f + bp[1];
        o0.z = (p0.z + v[2]) * 0.125f + bp[2];
        o0.w = (p0.w + v[3]) * 0.125f + bp[3];
        o1.x = (p1.x + v[4]) * 0.125f + bp[4];
        o1.y = (p1.y + v[5]) * 0.125f + bp[5];
        o1.z = (p1.z + v[6]) * 0.125f + bp[6];
        o1.w = (p1.w + v[7]) * 0.125f + bp[7];
        float* po = outbuf + (size_t)d * 64 + ll * 8;
        *(float4*)po = o0;
        *(float4*)(po + 4) = o1;
      }
    }
  }
}

extern "C" void kernel_launch(void* const* d_in, const int* in_sizes, int n_in,
                              void* d_out, int out_size, void* d_ws, size_t ws_size,
                              hipStream_t stream) {
  const float* x = (const float*)d_in[0];
  const int* ei = (const int*)d_in[1];
  const float* Wmat[3][2] = {
      {(const float*)d_in[2], (const float*)d_in[3]},
      {(const float*)d_in[6], (const float*)d_in[7]},
      {(const float*)d_in[10], (const float*)d_in[11]}};
  const float* att[3] = {(const float*)d_in[4], (const float*)d_in[8],
                         (const float*)d_in[12]};
  const float* bias[3] = {(const float*)d_in[5], (const float*)d_in[9],
                          (const float*)d_in[13]};
  const int N = NNODES;
  int E = in_sizes[1] / 2;

  auto al = [](size_t b) { return (b + 255) & ~(size_t)255; };
  size_t fixed = al((size_t)N * 64 * 4)                       // CUR
               + al((size_t)(N + 1) * 4) + al((size_t)N * 4)  // RS + CNT
               + al(512 * 4) + al((size_t)E * 4) + al((size_t)E);  // BSUM+SRC+RANK
  size_t need8 = fixed + 2 * al((size_t)N * 1024);
  bool mode8 = (ws_size >= need8);

  char* p = (char*)d_ws;
  auto alloc = [&](size_t bytes) {
    char* r = p;
    p += (bytes + 255) & ~(size_t)255;
    return r;
  };
  float* CUR = (float*)alloc((size_t)N * 64 * 4);
  size_t xtab = mode8 ? (size_t)N * 1024 : (size_t)N * 512;
  char* XL = alloc(xtab);
  char* XR = alloc(xtab);
  int* RS = (int*)alloc((size_t)(N + 1) * 4);
  int* CNT = (int*)alloc((size_t)N * 4);
  int* BSUM = (int*)alloc(512 * 4);
  int* SRC = (int*)alloc((size_t)E * 4);
  unsigned char* RANK = (unsigned char*)alloc((size_t)E);
  float* ACC = mode8 ? nullptr : (float*)alloc((size_t)N * 64 * 4);

  const int nb = (N + 255) / 256;
  const int geblk = (E + 255) / 256;
  const int g01 = (N + 15) / 16;
  const int gx64 = (N + 63) / 64;

  // ---- CSR build ----
  zeroi<<<nb, 256, 0, stream>>>(CNT, N);
  histrank<<<geblk, 256, 0, stream>>>(ei, E, CNT, RANK);
  scan1<<<nb, 256, 0, stream>>>(CNT, N, RS + 1, BSUM);
  scan2<<<1, 512, 0, stream>>>(BSUM, nb);
  scan3<<<nb, 256, 0, stream>>>(RS, BSUM, N);
  scat2<<<geblk, 256, 0, stream>>>(ei, E, RS, RANK, SRC);

  // ---- layers 0 and 1 (row stride 128B f16) ----
  for (int layer = 0; layer < 2; ++layer) {
    const float* in = (layer == 0) ? x : CUR;
    gemm_mfma<<<dim3(gx64, 1), 256, 0, stream>>>(
        in, Wmat[layer][0], Wmat[layer][1], XL, XR, N, 64, 0, 128u);
    fused01<<<g01, 256, 0, stream>>>(XL, XR, att[layer], RS, SRC, bias[layer],
                                     CUR, N, layer);
  }

  // ---- layer 2 ----
  if (mode8) {
    gemm_mfma<<<dim3(gx64, 8), 256, 0, stream>>>(
        CUR, Wmat[2][0], Wmat[2][1], XL, XR, N, 512, 0, 1024u);
    fused2<8><<<(N + 3) / 4, 256, 0, stream>>>(XL, XR, att[2], RS, SRC, bias[2],
                                               nullptr, (float*)d_out, N, 0, 0);
  } else {
    for (int hb = 0; hb < 2; ++hb) {
      gemm_mfma<<<dim3(gx64, 4), 256, 0, stream>>>(
          CUR, Wmat[2][0], Wmat[2][1], XL, XR, N, 512, hb * 256, 512u);
      fused2<4><<<(N + 7) / 8, 256, 0, stream>>>(XL, XR, att[2], RS, SRC, bias[2],
                                                 ACC, (float*)d_out, N, hb * 4, hb);
    }
  }
}

// Round 14
// 651.753 us; speedup vs baseline: 1.1254x; 1.0177x over previous
//
#include <hip/hip_runtime.h>
#include <hip/hip_fp16.h>
#include <math.h>

#define NNODES 100000

typedef _Float16 f16x2 __attribute__((ext_vector_type(2)));
typedef _Float16 f16x8 __attribute__((ext_vector_type(8)));
typedef float f32x4 __attribute__((ext_vector_type(4)));

#define LOG2E 1.44269504f
#define THR2 11.5415603f   // 8 * log2e

__device__ __forceinline__ float ex2(float x) {  // native 2^x
  float r;
  asm("v_exp_f32 %0, %1" : "=v"(r) : "v"(x));
  return r;
}
__device__ __forceinline__ f16x2 bch(unsigned x) {
  return __builtin_bit_cast(f16x2, x);
}
__device__ __forceinline__ float fdot2h(f16x2 a, f16x2 b, float c) {
#if __has_builtin(__builtin_amdgcn_fdot2)
  return __builtin_amdgcn_fdot2(a, b, c, false);
#else
  return c + (float)a.x * (float)b.x + (float)a.y * (float)b.y;
#endif
}
// acc(f32) += f16(lo/hi of xpk) * e(f32)  — single v_fma_mix_f32
__device__ __forceinline__ void fmix_lo(float& acc, unsigned xpk, float e) {
  asm("v_fma_mix_f32 %0, %1, %2, %0 op_sel_hi:[1,0,0]"
      : "+v"(acc) : "v"(xpk), "v"(e));
}
__device__ __forceinline__ void fmix_hi(float& acc, unsigned xpk, float e) {
  asm("v_fma_mix_f32 %0, %1, %2, %0 op_sel:[1,0,0] op_sel_hi:[1,0,0]"
      : "+v"(acc) : "v"(xpk), "v"(e));
}
// packed leaky-relu: max(v, 0.2*v) elementwise (v_pk_mul + v_pk_max)
__device__ __forceinline__ f16x2 pleaky(f16x2 v) {
  f16x2 w = v * (_Float16)0.2f;
  return __builtin_elementwise_max(v, w);
}

#define LDK 68  // padded LDS k-stride (f16): 2-way bank aliasing max (free)

// ---------- MFMA GEMM (f16): XL/XR rows [ncols f16], stride RB bytes ----------
__global__ __launch_bounds__(256) void gemm_mfma(const float* __restrict__ in,
                                                 const float* __restrict__ Wl,
                                                 const float* __restrict__ Wr,
                                                 char* __restrict__ XLb,
                                                 char* __restrict__ XRb,
                                                 int n, int fo, int col0,
                                                 unsigned RB) {
  __shared__ _Float16 sX[64][LDK];  // [row][k]
  __shared__ _Float16 sL[64][LDK];  // W transposed: [col][k]
  __shared__ _Float16 sR[64][LDK];
  int r0 = blockIdx.x * 64;
  int ct = blockIdx.y * 64;
  for (int i = threadIdx.x; i < 64 * 64; i += 256) {
    int r = i >> 6, k = i & 63;
    float v = (r0 + r < n) ? in[(size_t)(r0 + r) * 64 + k] : 0.f;
    sX[r][k] = (_Float16)v;
  }
  for (int i = threadIdx.x; i < 64 * 64; i += 256) {
    int k = i >> 6, c = i & 63;
    int gc = col0 + ct + c;
    sL[c][k] = (_Float16)Wl[k * fo + gc];
    sR[c][k] = (_Float16)Wr[k * fo + gc];
  }
  __syncthreads();
  int w = threadIdx.x >> 6, l = threadIdx.x & 63;
  int l16 = l & 15, kg = l >> 4;
  f16x8 a0 = *(const f16x8*)&sX[w * 16 + l16][kg * 8];
  f16x8 a1 = *(const f16x8*)&sX[w * 16 + l16][kg * 8 + 32];
  f32x4 accL[4], accR[4];
#pragma unroll
  for (int nt = 0; nt < 4; ++nt) {
#pragma unroll
    for (int r = 0; r < 4; ++r) { accL[nt][r] = 0.f; accR[nt][r] = 0.f; }
  }
#pragma unroll
  for (int nt = 0; nt < 4; ++nt) {
    f16x8 bl0 = *(const f16x8*)&sL[nt * 16 + l16][kg * 8];
    f16x8 bl1 = *(const f16x8*)&sL[nt * 16 + l16][kg * 8 + 32];
    f16x8 br0 = *(const f16x8*)&sR[nt * 16 + l16][kg * 8];
    f16x8 br1 = *(const f16x8*)&sR[nt * 16 + l16][kg * 8 + 32];
    accL[nt] = __builtin_amdgcn_mfma_f32_16x16x32_f16(a0, bl0, accL[nt], 0, 0, 0);
    accL[nt] = __builtin_amdgcn_mfma_f32_16x16x32_f16(a1, bl1, accL[nt], 0, 0, 0);
    accR[nt] = __builtin_amdgcn_mfma_f32_16x16x32_f16(a0, br0, accR[nt], 0, 0, 0);
    accR[nt] = __builtin_amdgcn_mfma_f32_16x16x32_f16(a1, br1, accR[nt], 0, 0, 0);
  }
  // D layout: col = l&15, row = (l>>4)*4 + reg
#pragma unroll
  for (int r = 0; r < 4; ++r) {
    int grow = r0 + w * 16 + kg * 4 + r;
    if (grow >= n) continue;
    char* rowL = XLb + (size_t)grow * RB;
    char* rowR = XRb + (size_t)grow * RB;
#pragma unroll
    for (int nt = 0; nt < 4; ++nt) {
      int chb = (ct + nt * 16 + l16) * 2;
      *(_Float16*)(rowL + chb) = (_Float16)accL[nt][r];
      *(_Float16*)(rowR + chb) = (_Float16)accR[nt][r];
    }
  }
}

// ---------- CSR build (atomic-free scatter via ranks) ----------
__global__ void zeroi(int* __restrict__ p, int n) {
  int i = blockIdx.x * blockDim.x + threadIdx.x;
  if (i < n) p[i] = 0;
}
__global__ void histrank(const int* __restrict__ ei, int E,
                         int* __restrict__ cnt, unsigned char* __restrict__ rank) {
  int e = blockIdx.x * blockDim.x + threadIdx.x;
  if (e < E) rank[e] = (unsigned char)atomicAdd(&cnt[ei[E + e]], 1);
}
__global__ void scan1(const int* __restrict__ cnt, int n,
                      int* __restrict__ scn, int* __restrict__ bsum) {
  __shared__ int sh[256];
  int t = threadIdx.x, i = blockIdx.x * 256 + t;
  int v = (i < n) ? cnt[i] : 0;
  sh[t] = v;
  __syncthreads();
  for (int off = 1; off < 256; off <<= 1) {
    int x = (t >= off) ? sh[t - off] : 0;
    __syncthreads();
    sh[t] += x;
    __syncthreads();
  }
  if (i < n) scn[i] = sh[t];
  if (t == 255) bsum[blockIdx.x] = sh[255];
}
__global__ void scan2(int* __restrict__ bsum, int nb) {
  __shared__ int sh[512];
  int t = threadIdx.x;
  sh[t] = (t < nb) ? bsum[t] : 0;
  __syncthreads();
  for (int off = 1; off < 512; off <<= 1) {
    int x = (t >= off) ? sh[t - off] : 0;
    __syncthreads();
    sh[t] += x;
    __syncthreads();
  }
  if (t < nb) bsum[t] = sh[t];
}
__global__ void scan3(int* __restrict__ RS, const int* __restrict__ bsum, int n) {
  int i = blockIdx.x * blockDim.x + threadIdx.x;
  if (i >= n) return;
  int b = i >> 8;
  int pre = (b > 0) ? bsum[b - 1] : 0;
  RS[i + 1] += pre;
  if (i == 0) RS[0] = 0;
}
__global__ void scat2(const int* __restrict__ ei, int E,
                      const int* __restrict__ RS,
                      const unsigned char* __restrict__ rank,
                      int* __restrict__ SRC) {
  int e = blockIdx.x * blockDim.x + threadIdx.x;
  if (e >= E) return;
  int d = ei[E + e];
  SRC[RS[d] + (int)rank[e]] = ei[e];
}

// ---------- fused layers 0/1 (C=8 concat): 4 dsts/wave; unroll-2 edge pairs ----------
__global__ __launch_bounds__(256) void fused01(const char* __restrict__ xlb,
                                               const char* __restrict__ xrb,
                                               const float* __restrict__ att, // [8][8]
                                               const int* __restrict__ RS,
                                               const int* __restrict__ SRC,
                                               const float* __restrict__ bias,
                                               float* __restrict__ curbuf,
                                               int n, int addres) {
  int l = threadIdx.x & 63;
  int q = l & 15;  // channel quad: ch 4q..4q+3
  int d = blockIdx.x * 16 + ((threadIdx.x >> 6) << 2) + (l >> 4);
  int dd = (d < n) ? d : 0;
  f16x2 c2a = {(_Float16)(att[4 * q] * LOG2E), (_Float16)(att[4 * q + 1] * LOG2E)};
  f16x2 c2b = {(_Float16)(att[4 * q + 2] * LOG2E), (_Float16)(att[4 * q + 3] * LOG2E)};
  uint2 ur = *(const uint2*)(xrb + ((unsigned)dd << 7) + (q << 3));
  f16x2 r2a = bch(ur.x), r2b = bch(ur.y);
  int rs = RS[dd], re = RS[dd + 1];
  int cnt = (d < n) ? (re - rs + 1) : 0;  // self loop + edges
  int mc = max(cnt, __shfl_xor(cnt, 16));
  mc = max(mc, __shfl_xor(mc, 32));
  float m = -1e30f, s = 0.f, ac0 = 0.f, ac1 = 0.f, ac2 = 0.f, ac3 = 0.f;
  // edge j: j==0 -> self (dd), else SRC[rs+j-1]
  int id1 = (rs < re) ? SRC[rs] : dd;
  uint2 u0 = *(const uint2*)(xlb + ((unsigned)dd << 7) + (q << 3));
  uint2 u1 = *(const uint2*)(xlb + ((unsigned)id1 << 7) + (q << 3));
  int id2 = (rs + 1 < re) ? SRC[rs + 1] : dd;
  int id3 = (rs + 2 < re) ? SRC[rs + 2] : dd;
  for (int j = 0;;) {
    uint2 u2 = *(const uint2*)(xlb + ((unsigned)id2 << 7) + (q << 3));
    uint2 u3 = *(const uint2*)(xlb + ((unsigned)id3 << 7) + (q << 3));
    int i4 = rs + j + 3, i5 = rs + j + 4;
    int id4 = (i4 < re) ? SRC[i4] : dd;
    int id5 = (i5 < re) ? SRC[i5] : dd;
    f16x2 laa = pleaky(bch(u0.x) + r2a);
    f16x2 lab = pleaky(bch(u0.y) + r2b);
    f16x2 lba = pleaky(bch(u1.x) + r2a);
    f16x2 lbb = pleaky(bch(u1.y) + r2b);
    float ta = fdot2h(lab, c2b, fdot2h(laa, c2a, 0.f));
    float tb = fdot2h(lbb, c2b, fdot2h(lba, c2a, 0.f));
    ta += __shfl_xor(ta, 1);
    tb += __shfl_xor(tb, 1);
    if (j >= cnt) ta = -1e30f;
    if (j + 1 >= cnt) tb = -1e30f;
    float tmx = fmaxf(ta, tb);
    if (__any(tmx > m + THR2)) {  // rare exact rescale (pair-shared)
      float nm = fmaxf(m, tmx);
      float e0 = ex2(m - nm);
      s *= e0; ac0 *= e0; ac1 *= e0; ac2 *= e0; ac3 *= e0; m = nm;
    }
    float ea = ex2(ta - m), eb = ex2(tb - m);
    s += ea + eb;
    fmix_lo(ac0, u0.x, ea);
    fmix_hi(ac1, u0.x, ea);
    fmix_lo(ac2, u0.y, ea);
    fmix_hi(ac3, u0.y, ea);
    fmix_lo(ac0, u1.x, eb);
    fmix_hi(ac1, u1.x, eb);
    fmix_lo(ac2, u1.y, eb);
    fmix_hi(ac3, u1.y, eb);
    j += 2;
    if (j >= mc) break;
    u0 = u2;
    u1 = u3;
    id2 = id4;
    id3 = id5;
  }
  if (d < n) {
    float inv = 1.f / (s + 1e-16f);
    float v0 = ac0 * inv + bias[4 * q];
    float v1 = ac1 * inv + bias[4 * q + 1];
    float v2 = ac2 * inv + bias[4 * q + 2];
    float v3 = ac3 * inv + bias[4 * q + 3];
    v0 = v0 > 0.f ? v0 : expm1f(v0);
    v1 = v1 > 0.f ? v1 : expm1f(v1);
    v2 = v2 > 0.f ? v2 : expm1f(v2);
    v3 = v3 > 0.f ? v3 : expm1f(v3);
    float4* pc = (float4*)(curbuf + (size_t)d * 64 + 4 * q);
    if (addres) {
      float4 pr = *pc;
      v0 += pr.x; v1 += pr.y; v2 += pr.z; v3 += pr.w;
    }
    *pc = make_float4(v0, v1, v2, v3);
  }
}

// ---------- fused layer 2 single-pass (8 heads, row 1024B, 1 dst/wave), unroll-2 ----------
__global__ __launch_bounds__(256) void fused2u(const char* __restrict__ xlb,
                                               const char* __restrict__ xrb,
                                               const float* __restrict__ att, // [8][64]
                                               const int* __restrict__ RS,
                                               const int* __restrict__ SRC,
                                               const float* __restrict__ bias,
                                               float* __restrict__ outbuf,
                                               int n) {
  int l = threadIdx.x & 63;
  int d = blockIdx.x * 4 + (threadIdx.x >> 6);
  int dd = (d < n) ? d : 0;
  int h = l >> 3, c0 = (l & 7) * 8;
  const float* ap = att + h * 64 + c0;
  f16x2 c2[4];
#pragma unroll
  for (int k = 0; k < 4; ++k)
    c2[k] = f16x2{(_Float16)(ap[2 * k] * LOG2E), (_Float16)(ap[2 * k + 1] * LOG2E)};
  uint4 ur = *(const uint4*)(xrb + ((unsigned)dd << 10) + (l << 4));
  f16x2 r2[4] = {bch(ur.x), bch(ur.y), bch(ur.z), bch(ur.w)};
  int rs = RS[dd], re = RS[dd + 1];
  int cnt = re - rs + 1;  // >= 1 (self loop)
  float m = -1e30f, s = 0.f;
  float ac[8] = {0.f, 0.f, 0.f, 0.f, 0.f, 0.f, 0.f, 0.f};
  int id1 = (rs < re) ? SRC[rs] : dd;
  uint4 u0 = *(const uint4*)(xlb + ((unsigned)dd << 10) + (l << 4));
  uint4 u1 = *(const uint4*)(xlb + ((unsigned)id1 << 10) + (l << 4));
  int id2 = (rs + 1 < re) ? SRC[rs + 1] : dd;
  int id3 = (rs + 2 < re) ? SRC[rs + 2] : dd;
  for (int j = 0;;) {
    uint4 u2 = *(const uint4*)(xlb + ((unsigned)id2 << 10) + (l << 4));
    uint4 u3 = *(const uint4*)(xlb + ((unsigned)id3 << 10) + (l << 4));
    int i4 = rs + j + 3, i5 = rs + j + 4;
    int id4 = (i4 < re) ? SRC[i4] : dd;
    int id5 = (i5 < re) ? SRC[i5] : dd;
    f16x2 a0 = pleaky(bch(u0.x) + r2[0]);
    f16x2 a1 = pleaky(bch(u0.y) + r2[1]);
    f16x2 a2 = pleaky(bch(u0.z) + r2[2]);
    f16x2 a3 = pleaky(bch(u0.w) + r2[3]);
    f16x2 b0 = pleaky(bch(u1.x) + r2[0]);
    f16x2 b1 = pleaky(bch(u1.y) + r2[1]);
    f16x2 b2 = pleaky(bch(u1.z) + r2[2]);
    f16x2 b3 = pleaky(bch(u1.w) + r2[3]);
    float ta = fdot2h(a3, c2[3], fdot2h(a2, c2[2], fdot2h(a1, c2[1], fdot2h(a0, c2[0], 0.f))));
    float tb = fdot2h(b3, c2[3], fdot2h(b2, c2[2], fdot2h(b1, c2[1], fdot2h(b0, c2[0], 0.f))));
    ta += __shfl_xor(ta, 1);
    tb += __shfl_xor(tb, 1);
    ta += __shfl_xor(ta, 2);
    tb += __shfl_xor(tb, 2);
    ta += __shfl_xor(ta, 4);
    tb += __shfl_xor(tb, 4);
    if (j + 1 >= cnt) tb = -1e30f;  // odd-count tail
    float tmx = fmaxf(ta, tb);
    if (__any(tmx > m + THR2)) {  // rare exact rescale (pair-shared)
      float nm = fmaxf(m, tmx);
      float e0 = ex2(m - nm);
      s *= e0;
#pragma unroll
      for (int k = 0; k < 8; ++k) ac[k] *= e0;
      m = nm;
    }
    float ea = ex2(ta - m), eb = ex2(tb - m);
    s += ea + eb;
    fmix_lo(ac[0], u0.x, ea);
    fmix_hi(ac[1], u0.x, ea);
    fmix_lo(ac[2], u0.y, ea);
    fmix_hi(ac[3], u0.y, ea);
    fmix_lo(ac[4], u0.z, ea);
    fmix_hi(ac[5], u0.z, ea);
    fmix_lo(ac[6], u0.w, ea);
    fmix_hi(ac[7], u0.w, ea);
    fmix_lo(ac[0], u1.x, eb);
    fmix_hi(ac[1], u1.x, eb);
    fmix_lo(ac[2], u1.y, eb);
    fmix_hi(ac[3], u1.y, eb);
    fmix_lo(ac[4], u1.z, eb);
    fmix_hi(ac[5], u1.z, eb);
    fmix_lo(ac[6], u1.w, eb);
    fmix_hi(ac[7], u1.w, eb);
    j += 2;
    if (j >= cnt) break;
    u0 = u2;
    u1 = u3;
    id2 = id4;
    id3 = id5;
  }
  float inv = 1.f / (s + 1e-16f);
  float v[8];
#pragma unroll
  for (int k = 0; k < 8; ++k) {
    v[k] = ac[k] * inv;
    v[k] += __shfl_xor(v[k], 8);    // sum 8 heads
    v[k] += __shfl_xor(v[k], 16);
    v[k] += __shfl_xor(v[k], 32);
  }
  if (l < 8 && d < n) {
    const float* bp = bias + l * 8;
    float4 o0, o1;
    o0.x = v[0] * 0.125f + bp[0];
    o0.y = v[1] * 0.125f + bp[1];
    o0.z = v[2] * 0.125f + bp[2];
    o0.w = v[3] * 0.125f + bp[3];
    o1.x = v[4] * 0.125f + bp[4];
    o1.y = v[5] * 0.125f + bp[5];
    o1.z = v[6] * 0.125f + bp[6];
    o1.w = v[7] * 0.125f + bp[7];
    float* po = outbuf + (size_t)d * 64 + l * 8;
    *(float4*)po = o0;
    *(float4*)(po + 4) = o1;
  }
}

// ---------- fused layer 2 fallback (NH=4, row 512B, 2 dsts/wave, two passes) ----------
__global__ __launch_bounds__(256) void fused2f(const char* __restrict__ xlb,
                                               const char* __restrict__ xrb,
                                               const float* __restrict__ att,
                                               const int* __restrict__ RS,
                                               const int* __restrict__ SRC,
                                               const float* __restrict__ bias,
                                               float* __restrict__ accbuf,
                                               float* __restrict__ outbuf,
                                               int n, int h0, int pass) {
  int l = threadIdx.x & 63;
  int ll = l & 31;
  int d = blockIdx.x * 8 + ((threadIdx.x >> 6) << 1) + (l >> 5);
  int dd = (d < n) ? d : 0;
  int h = ll >> 3, c0 = (ll & 7) * 8;
  const float* ap = att + (h0 + h) * 64 + c0;
  f16x2 c2[4];
#pragma unroll
  for (int k = 0; k < 4; ++k)
    c2[k] = f16x2{(_Float16)(ap[2 * k] * LOG2E), (_Float16)(ap[2 * k + 1] * LOG2E)};
  uint4 ur = *(const uint4*)(xrb + ((unsigned)dd << 9) + (ll << 4));
  f16x2 r2[4] = {bch(ur.x), bch(ur.y), bch(ur.z), bch(ur.w)};
  int rs = RS[dd], re = RS[dd + 1];
  int cnt = (d < n) ? (re - rs + 1) : 0;
  int maxcnt = max(cnt, __shfl_xor(cnt, 32));
  float m = -1e30f, s = 0.f;
  float ac[8] = {0.f, 0.f, 0.f, 0.f, 0.f, 0.f, 0.f, 0.f};
  int nsid = (rs < re) ? SRC[rs] : dd;
  uint4 u = *(const uint4*)(xlb + ((unsigned)dd << 9) + (ll << 4));
  for (int j = 0;;) {
    uint4 un = *(const uint4*)(xlb + ((unsigned)nsid << 9) + (ll << 4));
    int i2 = rs + j + 1;
    int nn = (i2 < re) ? SRC[i2] : dd;
    f16x2 l0 = pleaky(bch(u.x) + r2[0]);
    f16x2 l1 = pleaky(bch(u.y) + r2[1]);
    f16x2 l2 = pleaky(bch(u.z) + r2[2]);
    f16x2 l3 = pleaky(bch(u.w) + r2[3]);
    float t = fdot2h(l3, c2[3], fdot2h(l2, c2[2], fdot2h(l1, c2[1], fdot2h(l0, c2[0], 0.f))));
    t += __shfl_xor(t, 1);
    t += __shfl_xor(t, 2);
    t += __shfl_xor(t, 4);
    if (j >= cnt) t = -1e30f;
    if (__any(t > m + THR2)) {
      float nm = fmaxf(m, t);
      float e0 = ex2(m - nm);
      s *= e0;
#pragma unroll
      for (int k = 0; k < 8; ++k) ac[k] *= e0;
      m = nm;
    }
    float e1 = ex2(t - m);
    s += e1;
    fmix_lo(ac[0], u.x, e1);
    fmix_hi(ac[1], u.x, e1);
    fmix_lo(ac[2], u.y, e1);
    fmix_hi(ac[3], u.y, e1);
    fmix_lo(ac[4], u.z, e1);
    fmix_hi(ac[5], u.z, e1);
    fmix_lo(ac[6], u.w, e1);
    fmix_hi(ac[7], u.w, e1);
    ++j;
    if (j >= maxcnt) break;
    u = un;
    nsid = nn;
  }
  float inv = 1.f / (s + 1e-16f);
  float v[8];
#pragma unroll
  for (int k = 0; k < 8; ++k) {
    v[k] = ac[k] * inv;
    v[k] += __shfl_xor(v[k], 8);
    v[k] += __shfl_xor(v[k], 16);
  }
  if (ll < 8 && d < n) {
    float* pa = accbuf + (size_t)d * 64 + ll * 8;
    if (pass == 0) {
      *(float4*)pa = make_float4(v[0], v[1], v[2], v[3]);
      *(float4*)(pa + 4) = make_float4(v[4], v[5], v[6], v[7]);
    } else {
      float4 p0 = *(float4*)pa;
      float4 p1 = *(float4*)(pa + 4);
      const float* bp = bias + ll * 8;
      float4 o0, o1;
      o0.x = (p0.x + v[0]) * 0.125f + bp[0];
      o0.y = (p0.y + v[1]) * 0.125f + bp[1];
      o0.z = (p0.z + v[2]) * 0.125f + bp[2];
      o0.w = (p0.w + v[3]) * 0.125f + bp[3];
      o1.x = (p1.x + v[4]) * 0.125f + bp[4];
      o1.y = (p1.y + v[5]) * 0.125f + bp[5];
      o1.z = (p1.z + v[6]) * 0.125f + bp[6];
      o1.w = (p1.w + v[7]) * 0.125f + bp[7];
      float* po = outbuf + (size_t)d * 64 + ll * 8;
      *(float4*)po = o0;
      *(float4*)(po + 4) = o1;
    }
  }
}

extern "C" void kernel_launch(void* const* d_in, const int* in_sizes, int n_in,
                              void* d_out, int out_size, void* d_ws, size_t ws_size,
                              hipStream_t stream) {
  const float* x = (const float*)d_in[0];
  const int* ei = (const int*)d_in[1];
  const float* Wmat[3][2] = {
      {(const float*)d_in[2], (const float*)d_in[3]},
      {(const float*)d_in[6], (const float*)d_in[7]},
      {(const float*)d_in[10], (const float*)d_in[11]}};
  const float* att[3] = {(const float*)d_in[4], (const float*)d_in[8],
                         (const float*)d_in[12]};
  const float* bias[3] = {(const float*)d_in[5], (const float*)d_in[9],
                          (const float*)d_in[13]};
  const int N = NNODES;
  int E = in_sizes[1] / 2;

  auto al = [](size_t b) { return (b + 255) & ~(size_t)255; };
  size_t fixed = al((size_t)N * 64 * 4)                       // CUR
               + al((size_t)(N + 1) * 4) + al((size_t)N * 4)  // RS + CNT
               + al(512 * 4) + al((size_t)E * 4) + al((size_t)E);  // BSUM+SRC+RANK
  size_t need8 = fixed + 2 * al((size_t)N * 1024);
  bool mode8 = (ws_size >= need8);

  char* p = (char*)d_ws;
  auto alloc = [&](size_t bytes) {
    char* r = p;
    p += (bytes + 255) & ~(size_t)255;
    return r;
  };
  float* CUR = (float*)alloc((size_t)N * 64 * 4);
  size_t xtab = mode8 ? (size_t)N * 1024 : (size_t)N * 512;
  char* XL = alloc(xtab);
  char* XR = alloc(xtab);
  int* RS = (int*)alloc((size_t)(N + 1) * 4);
  int* CNT = (int*)alloc((size_t)N * 4);
  int* BSUM = (int*)alloc(512 * 4);
  int* SRC = (int*)alloc((size_t)E * 4);
  unsigned char* RANK = (unsigned char*)alloc((size_t)E);
  float* ACC = mode8 ? nullptr : (float*)alloc((size_t)N * 64 * 4);

  const int nb = (N + 255) / 256;
  const int geblk = (E + 255) / 256;
  const int g01 = (N + 15) / 16;
  const int gx64 = (N + 63) / 64;

  // ---- CSR build ----
  zeroi<<<nb, 256, 0, stream>>>(CNT, N);
  histrank<<<geblk, 256, 0, stream>>>(ei, E, CNT, RANK);
  scan1<<<nb, 256, 0, stream>>>(CNT, N, RS + 1, BSUM);
  scan2<<<1, 512, 0, stream>>>(BSUM, nb);
  scan3<<<nb, 256, 0, stream>>>(RS, BSUM, N);
  scat2<<<geblk, 256, 0, stream>>>(ei, E, RS, RANK, SRC);

  // ---- layers 0 and 1 (row stride 128B f16) ----
  for (int layer = 0; layer < 2; ++layer) {
    const float* in = (layer == 0) ? x : CUR;
    gemm_mfma<<<dim3(gx64, 1), 256, 0, stream>>>(
        in, Wmat[layer][0], Wmat[layer][1], XL, XR, N, 64, 0, 128u);
    fused01<<<g01, 256, 0, stream>>>(XL, XR, att[layer], RS, SRC, bias[layer],
                                     CUR, N, layer);
  }

  // ---- layer 2 ----
  if (mode8) {
    gemm_mfma<<<dim3(gx64, 8), 256, 0, stream>>>(
        CUR, Wmat[2][0], Wmat[2][1], XL, XR, N, 512, 0, 1024u);
    fused2u<<<(N + 3) / 4, 256, 0, stream>>>(XL, XR, att[2], RS, SRC, bias[2],
                                             (float*)d_out, N);
  } else {
    for (int hb = 0; hb < 2; ++hb) {
      gemm_mfma<<<dim3(gx64, 4), 256, 0, stream>>>(
          CUR, Wmat[2][0], Wmat[2][1], XL, XR, N, 512, hb * 256, 512u);
      fused2f<<<(N + 7) / 8, 256, 0, stream>>>(XL, XR, att[2], RS, SRC, bias[2],
                                               ACC, (float*)d_out, N, hb * 4, hb);
    }
  }
}